// Round 10
// baseline (109.760 us; speedup 1.0000x reference)
//
#include <hip/hip_runtime.h>
#include <math.h>

#define ALPHA 0.2f

constexpr int BB   = 4;
constexpr int NN_  = 4096;
constexpr int HN   = 2048;      // N/2
constexpr int FIN  = 128;
constexpr int FF   = 64;
constexpr int ROWS = BB * NN_;  // 16384
constexpr int NBLK = 256;       // == CU count; all blocks co-resident (1 block/CU)
constexpr int NT   = 512;       // 8 waves/block = 2 waves/SIMD

// ---- workspace layout (float offsets) ----
constexpr size_t WS_C    = 0;                        // ROWS   c = s1+s2 per row
constexpr size_t WS_E    = ROWS;                     // ROWS   e = even? s1 : s2
constexpr size_t WS_A0   = 2 * (size_t)ROWS;         // BB*FF
constexpr size_t WS_A1   = WS_A0 + (size_t)BB * FF;  // BB*FF
constexpr size_t WS_U    = WS_A1 + (size_t)BB * FF;  // BB*FF
constexpr size_t WS_M    = WS_U + (size_t)BB * FF;   // 2*BB
constexpr size_t WS_SYNC = WS_M + 2 * BB;            // 2 ints (barrier counters)

// Grid barrier: 1 block/CU -> all resident. Arrival = one device-scope RMW per
// block; poll = device-scope atomic LOAD (read, no ownership ping-pong).
// __threadfence release/acquire crosses the non-coherent per-XCD L2s; dirty
// set at the fences is only c/e (~130 KB), not 4 MB of h.
__device__ __forceinline__ void gbar(int* cnt, int tid) {
  __syncthreads();
  if (tid == 0) {
    __threadfence();                 // release
    __hip_atomic_fetch_add(cnt, 1, __ATOMIC_RELAXED, __HIP_MEMORY_SCOPE_AGENT);
    while (__hip_atomic_load(cnt, __ATOMIC_RELAXED, __HIP_MEMORY_SCOPE_AGENT) < NBLK)
      __builtin_amdgcn_s_sleep(4);
    __threadfence();                 // acquire
  }
  __syncthreads();
}

__global__ __launch_bounds__(NT, 2) void fused(const float* __restrict__ inp,
                                               const float* __restrict__ W,
                                               const float* __restrict__ a,
                                               float* __restrict__ ws,
                                               float* __restrict__ out) {
  const int tid  = threadIdx.x;
  const int lane = tid & 63;
  const int wv   = __builtin_amdgcn_readfirstlane(tid >> 6);   // 0..7
  const int blk  = blockIdx.x;
  int* cnt = (int*)(ws + WS_SYNC);

  __shared__ float rows_s[64 * FIN];   // 32 KB input staging
  __shared__ float redm[8][2];
  __shared__ float accbuf[8][2][64];   // 4 KB
  __shared__ float e_s[128];

  const int rowbase = blk * 64;
  float hreg[8];                       // this thread's h[row=wv*8+rr][col=lane]

  // ================= Phase A: h = inp @ W (h stays in registers) =================
  {
    float Wreg[FIN];
    #pragma unroll
    for (int k = 0; k < FIN; ++k) Wreg[k] = W[k * FF + lane];
    const float a1 = a[lane];
    const float a2 = a[FF + lane];
    const float asum = a1 + a2;

    const float4* src = reinterpret_cast<const float4*>(inp + (size_t)rowbase * FIN);
    float4* dst = reinterpret_cast<float4*>(rows_s);
    #pragma unroll
    for (int i = 0; i < 4; ++i) dst[tid + i * NT] = src[tid + i * NT];
    __syncthreads();

    // zero the 768 accumulator floats (replay-safe: phase-C atomics would
    // otherwise accumulate across graph replays). Ordered before C by gbar0.
    if (blk < 3 && tid < 256) ws[WS_A0 + (size_t)blk * 256 + tid] = 0.f;

    float* cout = ws + WS_C;
    float* eout = ws + WS_E;

    #pragma unroll
    for (int p = 0; p < 4; ++p) {
      const int lr0 = wv * 8 + 2 * p;              // local even row
      const float* rp0 = rows_s + lr0 * FIN;
      const float* rp1 = rp0 + FIN;
      float h0 = 0.f, h0b = 0.f, h1 = 0.f, h1b = 0.f;
      #pragma unroll
      for (int k = 0; k < FIN; k += 4) {
        const float4 x0 = *reinterpret_cast<const float4*>(rp0 + k);
        const float4 x1 = *reinterpret_cast<const float4*>(rp1 + k);
        h0  = fmaf(x0.x, Wreg[k],     h0);
        h0b = fmaf(x0.y, Wreg[k + 1], h0b);
        h0  = fmaf(x0.z, Wreg[k + 2], h0);
        h0b = fmaf(x0.w, Wreg[k + 3], h0b);
        h1  = fmaf(x1.x, Wreg[k],     h1);
        h1b = fmaf(x1.y, Wreg[k + 1], h1b);
        h1  = fmaf(x1.z, Wreg[k + 2], h1);
        h1b = fmaf(x1.w, Wreg[k + 3], h1b);
      }
      const float H0 = h0 + h0b;
      const float H1 = h1 + h1b;
      hreg[2 * p]     = H0;
      hreg[2 * p + 1] = H1;

      float c0 = H0 * asum, e0 = H0 * a1;   // even row -> s1
      float c1 = H1 * asum, e1 = H1 * a2;   // odd row  -> s2
      #pragma unroll
      for (int s = 32; s >= 1; s >>= 1) {
        c0 += __shfl_xor(c0, s, 64);
        e0 += __shfl_xor(e0, s, 64);
        c1 += __shfl_xor(c1, s, 64);
        e1 += __shfl_xor(e1, s, 64);
      }
      if (lane == 0) {
        const int r0 = rowbase + lr0;
        cout[r0] = c0;     eout[r0] = e0;
        cout[r0 + 1] = c1; eout[r0 + 1] = e1;
      }
    }
  }
  gbar(cnt + 0, tid);

  // ======== Phase C': per-batch stats (redundant per block) + weighted colsum ========
  const int b  = blk >> 6;                       // batch
  const int jb = rowbase & (NN_ - 1);            // within-batch column start (64-aligned)
  {
    const float* c = ws + WS_C + (size_t)b * NN_;
    const float* e = ws + WS_E + (size_t)b * NN_;

    // stage the 128 e-floats this block needs (coherent vector loads -> LDS)
    const int jp0 = jb & (HN - 1);
    if (tid < 32)
      reinterpret_cast<float4*>(e_s)[tid] =
          reinterpret_cast<const float4*>(e + 2 * jp0)[tid];

    // ---- stats: 512 threads x 8 c-values ----
    const float4 cv0 = reinterpret_cast<const float4*>(c)[2 * tid];
    const float4 cv1 = reinterpret_cast<const float4*>(c)[2 * tid + 1];
    const float l0 = cv0.x > 0.f ? cv0.x : ALPHA * cv0.x;
    const float l1 = cv0.y > 0.f ? cv0.y : ALPHA * cv0.y;
    const float l2 = cv0.z > 0.f ? cv0.z : ALPHA * cv0.z;
    const float l3 = cv0.w > 0.f ? cv0.w : ALPHA * cv0.w;
    const float l4 = cv1.x > 0.f ? cv1.x : ALPHA * cv1.x;
    const float l5 = cv1.y > 0.f ? cv1.y : ALPHA * cv1.y;
    const float l6 = cv1.z > 0.f ? cv1.z : ALPHA * cv1.z;
    const float l7 = cv1.w > 0.f ? cv1.w : ALPHA * cv1.w;
    float me = fmaxf(fmaxf(l0, l2), fmaxf(l4, l6));
    float mo = fmaxf(fmaxf(l1, l3), fmaxf(l5, l7));
    #pragma unroll
    for (int s = 32; s >= 1; s >>= 1) {
      me = fmaxf(me, __shfl_xor(me, s, 64));
      mo = fmaxf(mo, __shfl_xor(mo, s, 64));
    }
    if (lane == 0) { redm[wv][0] = me; redm[wv][1] = mo; }
    __syncthreads();
    float M0 = redm[0][0], M1 = redm[0][1];
    #pragma unroll
    for (int i = 1; i < 8; ++i) {
      M0 = fmaxf(M0, redm[i][0]);
      M1 = fmaxf(M1, redm[i][1]);
    }
    __syncthreads();
    float se = __expf(l0 - M0) + __expf(l2 - M0) + __expf(l4 - M0) + __expf(l6 - M0);
    float so = __expf(l1 - M1) + __expf(l3 - M1) + __expf(l5 - M1) + __expf(l7 - M1);
    #pragma unroll
    for (int s = 32; s >= 1; s >>= 1) {
      se += __shfl_xor(se, s, 64);
      so += __shfl_xor(so, s, 64);
    }
    if (lane == 0) { redm[wv][0] = se; redm[wv][1] = so; }
    __syncthreads();
    float P0 = 0.f, P1 = 0.f;
    #pragma unroll
    for (int i = 0; i < 8; ++i) { P0 += redm[i][0]; P1 += redm[i][1]; }

    if ((blk & 63) == 0 && tid == 0) {
      ws[WS_M + 2 * b]     = M0;
      ws[WS_M + 2 * b + 1] = M1;
    }

    // ---- weights + colsum over this block's 64 register-resident h rows ----
    const bool firstHalf = jb < HN;
    const float Mt = firstHalf ? M0 : M1;
    const float Pt = firstHalf ? P0 : P1;
    float accA = 0.f, accU = 0.f;
    #pragma unroll
    for (int rr = 0; rr < 8; ++rr) {
      const int li = wv * 8 + rr;                  // e_s-local column index
      const float d = e_s[2 * li] + e_s[2 * li + 1];
      const float v = d > 0.f ? d : ALPHA * d;
      const float m  = fmaxf(Mt, v);
      const float eM = __expf(Mt - m);
      const float ev = __expf(v - m);
      const float Z  = eM * Pt + (float)HN * ev;
      accA = fmaf(eM / Z, hreg[rr], accA);
      accU = fmaf(ev / Z, hreg[rr], accU);
    }
    accbuf[wv][0][lane] = accA;
    accbuf[wv][1][lane] = accU;
    __syncthreads();
    if (tid < 64) {
      float sA = 0.f, sU = 0.f;
      #pragma unroll
      for (int i = 0; i < 8; ++i) { sA += accbuf[i][0][tid]; sU += accbuf[i][1][tid]; }
      float* A = ws + (firstHalf ? WS_A0 : WS_A1) + (size_t)b * FF;
      atomicAdd(&A[tid], sA);
      atomicAdd(ws + WS_U + (size_t)b * FF + tid, sU);
    }
  }
  gbar(cnt + 1, tid);

  // ================= Phase D: rank-2 reconstruction + elu =================
  #pragma unroll
  for (int it = 0; it < 2; ++it) {
    const int idx = blk * 1024 + it * NT + tid;    // float4 group, B*N*16 total
    const int bo  = idx >> 16;
    const int rem = idx & 65535;
    const int i   = rem >> 4;
    const int fg  = rem & 15;
    float4 v;
    if (i < HN) {
      const float* c = ws + WS_C + (size_t)bo * NN_;
      const float M0 = ws[WS_M + 2 * bo];
      const float M1 = ws[WS_M + 2 * bo + 1];
      float c0 = c[2 * i], c1 = c[2 * i + 1];
      c0 = c0 > 0.f ? c0 : ALPHA * c0;
      c1 = c1 > 0.f ? c1 : ALPHA * c1;
      const float al = __expf(c0 - M0);
      const float be = __expf(c1 - M1);
      const float4 A0v = reinterpret_cast<const float4*>(ws + WS_A0 + (size_t)bo * FF)[fg];
      const float4 A1v = reinterpret_cast<const float4*>(ws + WS_A1 + (size_t)bo * FF)[fg];
      v.x = al * A0v.x + be * A1v.x;
      v.y = al * A0v.y + be * A1v.y;
      v.z = al * A0v.z + be * A1v.z;
      v.w = al * A0v.w + be * A1v.w;
    } else {
      v = reinterpret_cast<const float4*>(ws + WS_U + (size_t)bo * FF)[fg];
    }
    v.x = v.x > 0.f ? v.x : expm1f(v.x);
    v.y = v.y > 0.f ? v.y : expm1f(v.y);
    v.z = v.z > 0.f ? v.z : expm1f(v.z);
    v.w = v.w > 0.f ? v.w : expm1f(v.w);
    reinterpret_cast<float4*>(out)[idx] = v;
  }
}

extern "C" void kernel_launch(void* const* d_in, const int* in_sizes, int n_in,
                              void* d_out, int out_size, void* d_ws, size_t ws_size,
                              hipStream_t stream) {
  (void)in_sizes; (void)n_in; (void)out_size; (void)ws_size;
  const float* inp = (const float*)d_in[0];
  const float* W   = (const float*)d_in[1];
  const float* a   = (const float*)d_in[2];
  float* out = (float*)d_out;
  float* ws  = (float*)d_ws;

  // zero the barrier counters (stream-ordered, graph-capture-legal)
  hipMemsetAsync((char*)d_ws + WS_SYNC * sizeof(float), 0, 64, stream);
  hipLaunchKernelGGL(fused, dim3(NBLK), dim3(NT), 0, stream, inp, W, a, ws, out);
}

// Round 11
// 57.438 us; speedup vs baseline: 1.9109x; 1.9109x over previous
//
#include <hip/hip_runtime.h>
#include <math.h>

#define ALPHA 0.2f

constexpr int BB   = 4;
constexpr int NN_  = 4096;
constexpr int HN   = 2048;      // N/2
constexpr int FIN  = 128;
constexpr int FF   = 64;
constexpr int ROWS = BB * NN_;  // 16384
constexpr int NBLK = 256;       // == CU count; all blocks co-resident (1 block/CU)
constexpr int NT   = 256;       // 4 waves; plain launch_bounds -> no VGPR cap spill

// ---- workspace layout (float offsets) ----
constexpr size_t WS_C    = 0;                        // ROWS   c = s1+s2 per row
constexpr size_t WS_E    = ROWS;                     // ROWS   e = even? s1 : s2
constexpr size_t WS_A0   = 2 * (size_t)ROWS;         // BB*FF
constexpr size_t WS_A1   = WS_A0 + (size_t)BB * FF;  // BB*FF
constexpr size_t WS_U    = WS_A1 + (size_t)BB * FF;  // BB*FF
constexpr size_t WS_M    = WS_U + (size_t)BB * FF;   // 2*BB
constexpr size_t WS_SYNC = WS_M + 2 * BB;            // 2 ints (barrier counters)

// Grid barrier: 1 block/CU -> all resident. Arrival = one device-scope RMW per
// block; poll = device-scope atomic LOAD (no exclusive-ownership ping-pong).
__device__ __forceinline__ void gbar(int* cnt, int tid) {
  __syncthreads();
  if (tid == 0) {
    __threadfence();                 // release
    __hip_atomic_fetch_add(cnt, 1, __ATOMIC_RELAXED, __HIP_MEMORY_SCOPE_AGENT);
    while (__hip_atomic_load(cnt, __ATOMIC_RELAXED, __HIP_MEMORY_SCOPE_AGENT) < NBLK)
      __builtin_amdgcn_s_sleep(4);
    __threadfence();                 // acquire
  }
  __syncthreads();
}

__global__ __launch_bounds__(NT) void fused(const float* __restrict__ inp,
                                            const float* __restrict__ W,
                                            const float* __restrict__ a,
                                            float* __restrict__ ws,
                                            float* __restrict__ out) {
  const int tid  = threadIdx.x;
  const int lane = tid & 63;
  const int wv   = __builtin_amdgcn_readfirstlane(tid >> 6);   // 0..3
  const int blk  = blockIdx.x;
  int* cnt = (int*)(ws + WS_SYNC);

  __shared__ float rows_s[64 * FIN];   // 32 KB input staging
  __shared__ float redm[4][2];
  __shared__ float accbuf[4][2][64];   // 2 KB
  __shared__ float e_s[128];

  const int rowbase = blk * 64;
  float hreg[16];                      // h[row = wv*16 + rr][col = lane]

  // ================= Phase A: h = inp @ W (h stays in registers) =================
  {
    float Wreg[FIN];
    #pragma unroll
    for (int k = 0; k < FIN; ++k) Wreg[k] = W[k * FF + lane];
    const float a1 = a[lane];
    const float a2 = a[FF + lane];
    const float asum = a1 + a2;

    const float4* src = reinterpret_cast<const float4*>(inp + (size_t)rowbase * FIN);
    float4* dst = reinterpret_cast<float4*>(rows_s);
    #pragma unroll
    for (int i = 0; i < 8; ++i) dst[tid + i * NT] = src[tid + i * NT];
    __syncthreads();

    // zero the 768 accumulator floats (replay-safe: phase-C atomics would
    // otherwise accumulate across graph replays). Ordered before C by gbar0.
    if (blk < 3) ws[WS_A0 + (size_t)blk * 256 + tid] = 0.f;

    float* cout = ws + WS_C;
    float* eout = ws + WS_E;

    #pragma unroll
    for (int p = 0; p < 8; ++p) {
      const int lr0 = wv * 16 + 2 * p;             // local even row
      const float* rp0 = rows_s + lr0 * FIN;
      const float* rp1 = rp0 + FIN;
      float h0 = 0.f, h0b = 0.f, h1 = 0.f, h1b = 0.f;
      #pragma unroll
      for (int k = 0; k < FIN; k += 4) {
        const float4 x0 = *reinterpret_cast<const float4*>(rp0 + k);
        const float4 x1 = *reinterpret_cast<const float4*>(rp1 + k);
        h0  = fmaf(x0.x, Wreg[k],     h0);
        h0b = fmaf(x0.y, Wreg[k + 1], h0b);
        h0  = fmaf(x0.z, Wreg[k + 2], h0);
        h0b = fmaf(x0.w, Wreg[k + 3], h0b);
        h1  = fmaf(x1.x, Wreg[k],     h1);
        h1b = fmaf(x1.y, Wreg[k + 1], h1b);
        h1  = fmaf(x1.z, Wreg[k + 2], h1);
        h1b = fmaf(x1.w, Wreg[k + 3], h1b);
      }
      const float H0 = h0 + h0b;
      const float H1 = h1 + h1b;
      hreg[2 * p]     = H0;
      hreg[2 * p + 1] = H1;

      float c0 = H0 * asum, e0 = H0 * a1;   // even row -> s1
      float c1 = H1 * asum, e1 = H1 * a2;   // odd row  -> s2
      #pragma unroll
      for (int s = 32; s >= 1; s >>= 1) {
        c0 += __shfl_xor(c0, s, 64);
        e0 += __shfl_xor(e0, s, 64);
        c1 += __shfl_xor(c1, s, 64);
        e1 += __shfl_xor(e1, s, 64);
      }
      if (lane == 0) {
        const int r0 = rowbase + lr0;
        cout[r0] = c0;     eout[r0] = e0;
        cout[r0 + 1] = c1; eout[r0 + 1] = e1;
      }
    }
  }
  gbar(cnt + 0, tid);

  // ======== Phase C': per-batch stats (redundant per block) + weighted colsum ========
  const int b  = blk >> 6;                       // batch
  const int jb = rowbase & (NN_ - 1);            // within-batch column start (64-aligned)
  {
    const float* c = ws + WS_C + (size_t)b * NN_;
    const float* e = ws + WS_E + (size_t)b * NN_;

    // stage the 128 e-floats this block needs
    const int jp0 = jb & (HN - 1);
    if (tid < 32)
      reinterpret_cast<float4*>(e_s)[tid] =
          reinterpret_cast<const float4*>(e + 2 * jp0)[tid];

    // ---- stats: 256 threads x 16 c-values ----
    float l[16];
    float me = -INFINITY, mo = -INFINITY;
    #pragma unroll
    for (int q = 0; q < 4; ++q) {
      const float4 cv = reinterpret_cast<const float4*>(c)[4 * tid + q];
      float v0 = cv.x > 0.f ? cv.x : ALPHA * cv.x;
      float v1 = cv.y > 0.f ? cv.y : ALPHA * cv.y;
      float v2 = cv.z > 0.f ? cv.z : ALPHA * cv.z;
      float v3 = cv.w > 0.f ? cv.w : ALPHA * cv.w;
      l[4*q] = v0; l[4*q+1] = v1; l[4*q+2] = v2; l[4*q+3] = v3;
      me = fmaxf(me, fmaxf(v0, v2));
      mo = fmaxf(mo, fmaxf(v1, v3));
    }
    #pragma unroll
    for (int s = 32; s >= 1; s >>= 1) {
      me = fmaxf(me, __shfl_xor(me, s, 64));
      mo = fmaxf(mo, __shfl_xor(mo, s, 64));
    }
    if (lane == 0) { redm[wv][0] = me; redm[wv][1] = mo; }
    __syncthreads();
    const float M0 = fmaxf(fmaxf(redm[0][0], redm[1][0]), fmaxf(redm[2][0], redm[3][0]));
    const float M1 = fmaxf(fmaxf(redm[0][1], redm[1][1]), fmaxf(redm[2][1], redm[3][1]));
    __syncthreads();
    float se = 0.f, so = 0.f;
    #pragma unroll
    for (int q = 0; q < 8; ++q) {
      se += __expf(l[2*q]     - M0);
      so += __expf(l[2*q + 1] - M1);
    }
    #pragma unroll
    for (int s = 32; s >= 1; s >>= 1) {
      se += __shfl_xor(se, s, 64);
      so += __shfl_xor(so, s, 64);
    }
    if (lane == 0) { redm[wv][0] = se; redm[wv][1] = so; }
    __syncthreads();
    const float P0 = redm[0][0] + redm[1][0] + redm[2][0] + redm[3][0];
    const float P1 = redm[0][1] + redm[1][1] + redm[2][1] + redm[3][1];

    if ((blk & 63) == 0 && tid == 0) {
      ws[WS_M + 2 * b]     = M0;
      ws[WS_M + 2 * b + 1] = M1;
    }

    // ---- weights + colsum over this block's 64 register-resident h rows ----
    const bool firstHalf = jb < HN;
    const float Mt = firstHalf ? M0 : M1;
    const float Pt = firstHalf ? P0 : P1;
    float accA = 0.f, accU = 0.f;
    #pragma unroll
    for (int rr = 0; rr < 16; ++rr) {
      const int li = wv * 16 + rr;                 // e_s-local column index
      const float d = e_s[2 * li] + e_s[2 * li + 1];
      const float v = d > 0.f ? d : ALPHA * d;
      const float m  = fmaxf(Mt, v);
      const float eM = __expf(Mt - m);
      const float ev = __expf(v - m);
      const float Z  = eM * Pt + (float)HN * ev;
      accA = fmaf(eM / Z, hreg[rr], accA);
      accU = fmaf(ev / Z, hreg[rr], accU);
    }
    accbuf[wv][0][lane] = accA;
    accbuf[wv][1][lane] = accU;
    __syncthreads();
    if (tid < 64) {
      const float sA = accbuf[0][0][tid] + accbuf[1][0][tid] + accbuf[2][0][tid] + accbuf[3][0][tid];
      const float sU = accbuf[0][1][tid] + accbuf[1][1][tid] + accbuf[2][1][tid] + accbuf[3][1][tid];
      float* A = ws + (firstHalf ? WS_A0 : WS_A1) + (size_t)b * FF;
      atomicAdd(&A[tid], sA);
      atomicAdd(ws + WS_U + (size_t)b * FF + tid, sU);
    }
  }
  gbar(cnt + 1, tid);

  // ================= Phase D: rank-2 reconstruction + elu =================
  #pragma unroll
  for (int it = 0; it < 4; ++it) {
    const int idx = blk * 1024 + it * NT + tid;    // float4 group, B*N*16 total
    const int bo  = idx >> 16;
    const int rem = idx & 65535;
    const int i   = rem >> 4;
    const int fg  = rem & 15;
    float4 v;
    if (i < HN) {
      const float* c = ws + WS_C + (size_t)bo * NN_;
      const float M0 = ws[WS_M + 2 * bo];
      const float M1 = ws[WS_M + 2 * bo + 1];
      float c0 = c[2 * i], c1 = c[2 * i + 1];
      c0 = c0 > 0.f ? c0 : ALPHA * c0;
      c1 = c1 > 0.f ? c1 : ALPHA * c1;
      const float al = __expf(c0 - M0);
      const float be = __expf(c1 - M1);
      const float4 A0v = reinterpret_cast<const float4*>(ws + WS_A0 + (size_t)bo * FF)[fg];
      const float4 A1v = reinterpret_cast<const float4*>(ws + WS_A1 + (size_t)bo * FF)[fg];
      v.x = al * A0v.x + be * A1v.x;
      v.y = al * A0v.y + be * A1v.y;
      v.z = al * A0v.z + be * A1v.z;
      v.w = al * A0v.w + be * A1v.w;
    } else {
      v = reinterpret_cast<const float4*>(ws + WS_U + (size_t)bo * FF)[fg];
    }
    v.x = v.x > 0.f ? v.x : expm1f(v.x);
    v.y = v.y > 0.f ? v.y : expm1f(v.y);
    v.z = v.z > 0.f ? v.z : expm1f(v.z);
    v.w = v.w > 0.f ? v.w : expm1f(v.w);
    reinterpret_cast<float4*>(out)[idx] = v;
  }
}

extern "C" void kernel_launch(void* const* d_in, const int* in_sizes, int n_in,
                              void* d_out, int out_size, void* d_ws, size_t ws_size,
                              hipStream_t stream) {
  (void)in_sizes; (void)n_in; (void)out_size; (void)ws_size;
  const float* inp = (const float*)d_in[0];
  const float* W   = (const float*)d_in[1];
  const float* a   = (const float*)d_in[2];
  float* out = (float*)d_out;
  float* ws  = (float*)d_ws;

  // zero the barrier counters (stream-ordered, graph-capture-legal)
  hipMemsetAsync((char*)d_ws + WS_SYNC * sizeof(float), 0, 64, stream);
  hipLaunchKernelGGL(fused, dim3(NBLK), dim3(NT), 0, stream, inp, W, a, ws, out);
}

// Round 12
// 40.025 us; speedup vs baseline: 2.7423x; 1.4351x over previous
//
#include <hip/hip_runtime.h>
#include <math.h>

#define ALPHA 0.2f

constexpr int BB   = 4;
constexpr int NN_  = 4096;
constexpr int HN   = 2048;      // N/2
constexpr int FIN  = 128;
constexpr int FF   = 64;
constexpr int ROWS = BB * NN_;  // 16384
constexpr int NBLK = 256;       // == CU count; all blocks co-resident (1 block/CU)
constexpr int NT   = 256;       // 4 waves
constexpr int BPB  = 64;        // blocks per batch

// ---- workspace layout (float offsets) ----
constexpr size_t WS_C   = 0;                         // ROWS  c = s1+s2 per row
constexpr size_t WS_E   = ROWS;                      // ROWS  e = even? s1 : s2
constexpr size_t WS_A0  = 2 * (size_t)ROWS;          // BB*FF   (atomicAdd targets)
constexpr size_t WS_A1  = WS_A0 + (size_t)BB * FF;
constexpr size_t WS_U   = WS_A1 + (size_t)BB * FF;
constexpr size_t WS_CNT = WS_U + (size_t)BB * FF;    // 8 cachelines of counters
// memset covers [WS_A0, WS_CNT + 128 ints) = 768*4 + 512 bytes

// Per-batch barrier: 64 blocks, own cacheline. Arrival = release RMW (orders
// the wave's prior sc-stores / atomics); poll = acquire atomic LOAD.
__device__ __forceinline__ void batch_bar(int* cnt, int tid) {
  __syncthreads();   // all waves drain outstanding stores (vmcnt(0) before s_barrier)
  if (tid == 0) {
    __hip_atomic_fetch_add(cnt, 1, __ATOMIC_RELEASE, __HIP_MEMORY_SCOPE_AGENT);
    while (__hip_atomic_load(cnt, __ATOMIC_ACQUIRE, __HIP_MEMORY_SCOPE_AGENT) < BPB)
      __builtin_amdgcn_s_sleep(2);
  }
  __syncthreads();
}

__global__ __launch_bounds__(NT) void fused(const float* __restrict__ inp,
                                            const float* __restrict__ W,
                                            const float* __restrict__ a,
                                            float* __restrict__ ws,
                                            float* __restrict__ out) {
  const int tid  = threadIdx.x;
  const int lane = tid & 63;
  const int wv   = __builtin_amdgcn_readfirstlane(tid >> 6);   // 0..3
  const int blk  = blockIdx.x;
  const int b    = blk >> 6;                    // batch
  const int rowbase = blk * 64;
  const int jb   = rowbase & (NN_ - 1);         // within-batch row/col start
  const bool firstHalf = jb < HN;
  int* cd = (int*)(ws + WS_CNT) + b * 16;       // c/e-ready counter (own line)
  int* ad = (int*)(ws + WS_CNT) + (4 + b) * 16; // acc-ready counter (own line)

  __shared__ float rows_s[64 * FIN];   // 32 KB input staging
  __shared__ float redm[4][2];
  __shared__ float accbuf[4][2][64];
  __shared__ float e_s[128];

  float hreg[16];                      // h[row = wv*16 + rr][col = lane]

  // ================= Phase A: h = inp @ W (h stays in registers) =================
  {
    float Wreg[FIN];
    #pragma unroll
    for (int k = 0; k < FIN; ++k) Wreg[k] = W[k * FF + lane];
    const float a1 = a[lane];
    const float a2 = a[FF + lane];
    const float asum = a1 + a2;

    const float4* src = reinterpret_cast<const float4*>(inp + (size_t)rowbase * FIN);
    float4* dst = reinterpret_cast<float4*>(rows_s);
    #pragma unroll
    for (int i = 0; i < 8; ++i) dst[tid + i * NT] = src[tid + i * NT];
    __syncthreads();

    float* cout = ws + WS_C;
    float* eout = ws + WS_E;

    #pragma unroll
    for (int p = 0; p < 8; ++p) {
      const int lr0 = wv * 16 + 2 * p;             // local even row
      const float* rp0 = rows_s + lr0 * FIN;
      const float* rp1 = rp0 + FIN;
      float h0 = 0.f, h0b = 0.f, h1 = 0.f, h1b = 0.f;
      #pragma unroll
      for (int k = 0; k < FIN; k += 4) {
        const float4 x0 = *reinterpret_cast<const float4*>(rp0 + k);
        const float4 x1 = *reinterpret_cast<const float4*>(rp1 + k);
        h0  = fmaf(x0.x, Wreg[k],     h0);
        h0b = fmaf(x0.y, Wreg[k + 1], h0b);
        h0  = fmaf(x0.z, Wreg[k + 2], h0);
        h0b = fmaf(x0.w, Wreg[k + 3], h0b);
        h1  = fmaf(x1.x, Wreg[k],     h1);
        h1b = fmaf(x1.y, Wreg[k + 1], h1b);
        h1  = fmaf(x1.z, Wreg[k + 2], h1);
        h1b = fmaf(x1.w, Wreg[k + 3], h1b);
      }
      const float H0 = h0 + h0b;
      const float H1 = h1 + h1b;
      hreg[2 * p]     = H0;
      hreg[2 * p + 1] = H1;

      float c0 = H0 * asum, e0 = H0 * a1;   // even row -> s1
      float c1 = H1 * asum, e1 = H1 * a2;   // odd row  -> s2
      #pragma unroll
      for (int s = 32; s >= 1; s >>= 1) {
        c0 += __shfl_xor(c0, s, 64);
        e0 += __shfl_xor(e0, s, 64);
        c1 += __shfl_xor(c1, s, 64);
        e1 += __shfl_xor(e1, s, 64);
      }
      if (lane == 0) {
        const int r0 = rowbase + lr0;
        // write-through (bypass L2) -> visible at coherent point, no fence needed
        __hip_atomic_store(cout + r0,     c0, __ATOMIC_RELAXED, __HIP_MEMORY_SCOPE_AGENT);
        __hip_atomic_store(cout + r0 + 1, c1, __ATOMIC_RELAXED, __HIP_MEMORY_SCOPE_AGENT);
        __hip_atomic_store(eout + r0,     e0, __ATOMIC_RELAXED, __HIP_MEMORY_SCOPE_AGENT);
        __hip_atomic_store(eout + r0 + 1, e1, __ATOMIC_RELAXED, __HIP_MEMORY_SCOPE_AGENT);
      }
    }
  }
  batch_bar(cd, tid);   // c/e of this batch complete & visible

  // ======== Phase C': per-batch stats (redundant per block) + weighted colsum ========
  float M0, M1;
  {
    const float* c = ws + WS_C + (size_t)b * NN_;
    const float* e = ws + WS_E + (size_t)b * NN_;

    // stage the 128 e-floats this block needs (first touch -> miss to coherent point)
    const int jp0 = jb & (HN - 1);
    if (tid < 32)
      reinterpret_cast<float4*>(e_s)[tid] =
          reinterpret_cast<const float4*>(e + 2 * jp0)[tid];

    // ---- stats: 256 threads x 16 c-values ----
    float l[16];
    float me = -INFINITY, mo = -INFINITY;
    #pragma unroll
    for (int q = 0; q < 4; ++q) {
      const float4 cv = reinterpret_cast<const float4*>(c)[4 * tid + q];
      float v0 = cv.x > 0.f ? cv.x : ALPHA * cv.x;
      float v1 = cv.y > 0.f ? cv.y : ALPHA * cv.y;
      float v2 = cv.z > 0.f ? cv.z : ALPHA * cv.z;
      float v3 = cv.w > 0.f ? cv.w : ALPHA * cv.w;
      l[4*q] = v0; l[4*q+1] = v1; l[4*q+2] = v2; l[4*q+3] = v3;
      me = fmaxf(me, fmaxf(v0, v2));
      mo = fmaxf(mo, fmaxf(v1, v3));
    }
    #pragma unroll
    for (int s = 32; s >= 1; s >>= 1) {
      me = fmaxf(me, __shfl_xor(me, s, 64));
      mo = fmaxf(mo, __shfl_xor(mo, s, 64));
    }
    if (lane == 0) { redm[wv][0] = me; redm[wv][1] = mo; }
    __syncthreads();
    M0 = fmaxf(fmaxf(redm[0][0], redm[1][0]), fmaxf(redm[2][0], redm[3][0]));
    M1 = fmaxf(fmaxf(redm[0][1], redm[1][1]), fmaxf(redm[2][1], redm[3][1]));
    __syncthreads();
    float se = 0.f, so = 0.f;
    #pragma unroll
    for (int q = 0; q < 8; ++q) {
      se += __expf(l[2*q]     - M0);
      so += __expf(l[2*q + 1] - M1);
    }
    #pragma unroll
    for (int s = 32; s >= 1; s >>= 1) {
      se += __shfl_xor(se, s, 64);
      so += __shfl_xor(so, s, 64);
    }
    if (lane == 0) { redm[wv][0] = se; redm[wv][1] = so; }
    __syncthreads();
    const float P0 = redm[0][0] + redm[1][0] + redm[2][0] + redm[3][0];
    const float P1 = redm[0][1] + redm[1][1] + redm[2][1] + redm[3][1];

    // ---- weights + colsum over this block's 64 register-resident h rows ----
    const float Mt = firstHalf ? M0 : M1;
    const float Pt = firstHalf ? P0 : P1;
    float accA = 0.f, accU = 0.f;
    #pragma unroll
    for (int rr = 0; rr < 16; ++rr) {
      const int li = wv * 16 + rr;                 // e_s-local column index
      const float d = e_s[2 * li] + e_s[2 * li + 1];
      const float v = d > 0.f ? d : ALPHA * d;
      const float m  = fmaxf(Mt, v);
      const float eM = __expf(Mt - m);
      const float ev = __expf(v - m);
      const float Z  = eM * Pt + (float)HN * ev;
      accA = fmaf(eM / Z, hreg[rr], accA);
      accU = fmaf(ev / Z, hreg[rr], accU);
    }
    accbuf[wv][0][lane] = accA;
    accbuf[wv][1][lane] = accU;
    __syncthreads();
    if (tid < 64) {
      const float sA = accbuf[0][0][tid] + accbuf[1][0][tid] + accbuf[2][0][tid] + accbuf[3][0][tid];
      const float sU = accbuf[0][1][tid] + accbuf[1][1][tid] + accbuf[2][1][tid] + accbuf[3][1][tid];
      float* A = ws + (firstHalf ? WS_A0 : WS_A1) + (size_t)b * FF;
      atomicAdd(&A[tid], sA);                       // device-coherent RMWs
      atomicAdd(ws + WS_U + (size_t)b * FF + tid, sU);
    }
  }
  batch_bar(ad, tid);   // A0/A1/u of this batch complete

  // ========== Phase D: each block writes its OWN 64 rows (per-batch data) ==========
  {
    float4* out4 = reinterpret_cast<float4*>(out);
    if (firstHalf) {
      const float* c = ws + WS_C + (size_t)b * NN_;
      const float4* A04 = reinterpret_cast<const float4*>(ws + WS_A0 + (size_t)b * FF);
      const float4* A14 = reinterpret_cast<const float4*>(ws + WS_A1 + (size_t)b * FF);
      #pragma unroll
      for (int it = 0; it < 4; ++it) {
        const int t    = it * NT + tid;          // 0..1023
        const int rloc = t >> 4;
        const int fg   = t & 15;
        const int i    = jb + rloc;              // row within batch (top half)
        float c0 = c[2 * i], c1 = c[2 * i + 1];  // L2-hot normal loads
        c0 = c0 > 0.f ? c0 : ALPHA * c0;
        c1 = c1 > 0.f ? c1 : ALPHA * c1;
        const float al = __expf(c0 - M0);
        const float be = __expf(c1 - M1);
        const float4 A0v = A04[fg];
        const float4 A1v = A14[fg];
        float4 v;
        v.x = al * A0v.x + be * A1v.x;
        v.y = al * A0v.y + be * A1v.y;
        v.z = al * A0v.z + be * A1v.z;
        v.w = al * A0v.w + be * A1v.w;
        v.x = v.x > 0.f ? v.x : expm1f(v.x);
        v.y = v.y > 0.f ? v.y : expm1f(v.y);
        v.z = v.z > 0.f ? v.z : expm1f(v.z);
        v.w = v.w > 0.f ? v.w : expm1f(v.w);
        out4[((size_t)b * NN_ + i) * 16 + fg] = v;
      }
    } else {
      const float4* U4 = reinterpret_cast<const float4*>(ws + WS_U + (size_t)b * FF);
      #pragma unroll
      for (int it = 0; it < 4; ++it) {
        const int t    = it * NT + tid;
        const int rloc = t >> 4;
        const int fg   = t & 15;
        const int i    = jb + rloc;
        float4 v = U4[fg];
        v.x = v.x > 0.f ? v.x : expm1f(v.x);
        v.y = v.y > 0.f ? v.y : expm1f(v.y);
        v.z = v.z > 0.f ? v.z : expm1f(v.z);
        v.w = v.w > 0.f ? v.w : expm1f(v.w);
        out4[((size_t)b * NN_ + i) * 16 + fg] = v;
      }
    }
  }
}

extern "C" void kernel_launch(void* const* d_in, const int* in_sizes, int n_in,
                              void* d_out, int out_size, void* d_ws, size_t ws_size,
                              hipStream_t stream) {
  (void)in_sizes; (void)n_in; (void)out_size; (void)ws_size;
  const float* inp = (const float*)d_in[0];
  const float* W   = (const float*)d_in[1];
  const float* a   = (const float*)d_in[2];
  float* out = (float*)d_out;
  float* ws  = (float*)d_ws;

  // zero A0/A1/U accumulators + all barrier counters (replay-safe, stream-ordered)
  hipMemsetAsync((char*)d_ws + WS_A0 * sizeof(float), 0,
                 (3 * BB * FF) * sizeof(float) + 512, stream);
  hipLaunchKernelGGL(fused, dim3(NBLK), dim3(NT), 0, stream, inp, W, a, ws, out);
}

// Round 14
// 37.866 us; speedup vs baseline: 2.8987x; 1.0570x over previous
//
#include <hip/hip_runtime.h>
#include <math.h>

#define ALPHA 0.2f

constexpr int BB   = 4;
constexpr int NN_  = 4096;
constexpr int HN   = 2048;      // N/2
constexpr int FIN  = 128;
constexpr int FF   = 64;
constexpr int ROWS = BB * NN_;  // 16384
constexpr int NBLK = 256;       // == CU count; all blocks co-resident (1 block/CU)
constexpr int NT   = 256;       // 4 waves
constexpr int BPB  = 64;        // blocks per batch

// ---- workspace layout (float offsets) ----
constexpr size_t WS_C   = 0;                         // ROWS  c = s1+s2 per row
constexpr size_t WS_E   = ROWS;                      // ROWS  e = even? s1 : s2
constexpr size_t WS_A0  = 2 * (size_t)ROWS;          // BB*FF   (atomicAdd targets)
constexpr size_t WS_A1  = WS_A0 + (size_t)BB * FF;
constexpr size_t WS_U   = WS_A1 + (size_t)BB * FF;
constexpr size_t WS_FLG = WS_U + (size_t)BB * FF;    // BB*64 int flags (epoch barrier)
// memset covers [WS_A0, WS_FLG + BB*64 ints) = (768 + 256) * 4 = 4096 bytes

// Per-batch flag barrier: each of the 64 blocks owns ONE flag slot -> arrival
// is a single parallel write-through store (no RMW cacheline serialization).
// Wave 0's 64 lanes poll all 64 flags with one coalesced load per iteration;
// the final ACQUIRE load invalidates L1/L2 before post-barrier data reads.
// Epochs are monotonic within a call; the launch-side memset re-zeroes flags
// per call, so graph replays are safe.
__device__ __forceinline__ void flag_bar(int* flags, int slot, int epoch,
                                         int tid, int lane) {
  __syncthreads();   // drain this block's stores (vmcnt(0)) before signaling
  if (tid == 0)
    __hip_atomic_store(&flags[slot], epoch, __ATOMIC_RELAXED,
                       __HIP_MEMORY_SCOPE_AGENT);
  if (tid < 64) {
    while (__hip_atomic_load(&flags[lane], __ATOMIC_ACQUIRE,
                             __HIP_MEMORY_SCOPE_AGENT) < epoch)
      __builtin_amdgcn_s_sleep(2);
  }
  __syncthreads();
}

__global__ __launch_bounds__(NT) void fused(const float* __restrict__ inp,
                                            const float* __restrict__ W,
                                            const float* __restrict__ a,
                                            float* __restrict__ ws,
                                            float* __restrict__ out) {
  const int tid  = threadIdx.x;
  const int lane = tid & 63;
  const int wv   = __builtin_amdgcn_readfirstlane(tid >> 6);   // 0..3
  const int blk  = blockIdx.x;
  const int b    = blk >> 6;                    // batch
  const int slot = blk & 63;                    // this block's flag slot
  const int rowbase = blk * 64;
  const int jb   = rowbase & (NN_ - 1);         // within-batch row/col start
  const bool firstHalf = jb < HN;
  int* flags = (int*)(ws + WS_FLG) + b * 64;

  __shared__ float rows_s[64 * FIN];   // 32 KB input staging
  __shared__ float redm[4][2];
  __shared__ float accbuf[4][2][64];
  __shared__ float e_s[128];

  float hreg[16];                      // h[row = wv*16 + rr][col = lane]

  // ================= Phase A: h = inp @ W (h stays in registers) =================
  {
    float Wreg[FIN];
    #pragma unroll
    for (int k = 0; k < FIN; ++k) Wreg[k] = W[k * FF + lane];
    const float a1 = a[lane];
    const float a2 = a[FF + lane];
    const float asum = a1 + a2;

    const float4* src = reinterpret_cast<const float4*>(inp + (size_t)rowbase * FIN);
    float4* dst = reinterpret_cast<float4*>(rows_s);
    #pragma unroll
    for (int i = 0; i < 8; ++i) dst[tid + i * NT] = src[tid + i * NT];
    __syncthreads();

    float* cout = ws + WS_C;
    float* eout = ws + WS_E;

    #pragma unroll
    for (int p = 0; p < 8; ++p) {
      const int lr0 = wv * 16 + 2 * p;             // local even row
      const float* rp0 = rows_s + lr0 * FIN;
      const float* rp1 = rp0 + FIN;
      float h0 = 0.f, h0b = 0.f, h1 = 0.f, h1b = 0.f;
      #pragma unroll
      for (int k = 0; k < FIN; k += 4) {
        const float4 x0 = *reinterpret_cast<const float4*>(rp0 + k);
        const float4 x1 = *reinterpret_cast<const float4*>(rp1 + k);
        h0  = fmaf(x0.x, Wreg[k],     h0);
        h0b = fmaf(x0.y, Wreg[k + 1], h0b);
        h0  = fmaf(x0.z, Wreg[k + 2], h0);
        h0b = fmaf(x0.w, Wreg[k + 3], h0b);
        h1  = fmaf(x1.x, Wreg[k],     h1);
        h1b = fmaf(x1.y, Wreg[k + 1], h1b);
        h1  = fmaf(x1.z, Wreg[k + 2], h1);
        h1b = fmaf(x1.w, Wreg[k + 3], h1b);
      }
      const float H0 = h0 + h0b;
      const float H1 = h1 + h1b;
      hreg[2 * p]     = H0;
      hreg[2 * p + 1] = H1;

      float c0 = H0 * asum, e0 = H0 * a1;   // even row -> s1
      float c1 = H1 * asum, e1 = H1 * a2;   // odd row  -> s2
      #pragma unroll
      for (int s = 32; s >= 1; s >>= 1) {
        c0 += __shfl_xor(c0, s, 64);
        e0 += __shfl_xor(e0, s, 64);
        c1 += __shfl_xor(c1, s, 64);
        e1 += __shfl_xor(e1, s, 64);
      }
      if (lane == 0) {
        const int r0 = rowbase + lr0;
        // write-through (bypass L2) -> visible at coherent point, no fence needed
        __hip_atomic_store(cout + r0,     c0, __ATOMIC_RELAXED, __HIP_MEMORY_SCOPE_AGENT);
        __hip_atomic_store(cout + r0 + 1, c1, __ATOMIC_RELAXED, __HIP_MEMORY_SCOPE_AGENT);
        __hip_atomic_store(eout + r0,     e0, __ATOMIC_RELAXED, __HIP_MEMORY_SCOPE_AGENT);
        __hip_atomic_store(eout + r0 + 1, e1, __ATOMIC_RELAXED, __HIP_MEMORY_SCOPE_AGENT);
      }
    }
  }
  flag_bar(flags, slot, 1, tid, lane);   // c/e of this batch complete & visible

  // ======== Phase C': per-batch stats (redundant per block) + weighted colsum ========
  float M0, M1;
  {
    const float* c = ws + WS_C + (size_t)b * NN_;
    const float* e = ws + WS_E + (size_t)b * NN_;

    // stage the 128 e-floats this block needs (first touch -> miss to coherent point)
    const int jp0 = jb & (HN - 1);
    if (tid < 32)
      reinterpret_cast<float4*>(e_s)[tid] =
          reinterpret_cast<const float4*>(e + 2 * jp0)[tid];

    // ---- stats: 256 threads x 16 c-values ----
    float l[16];
    float me = -INFINITY, mo = -INFINITY;
    #pragma unroll
    for (int q = 0; q < 4; ++q) {
      const float4 cv = reinterpret_cast<const float4*>(c)[4 * tid + q];
      float v0 = cv.x > 0.f ? cv.x : ALPHA * cv.x;
      float v1 = cv.y > 0.f ? cv.y : ALPHA * cv.y;
      float v2 = cv.z > 0.f ? cv.z : ALPHA * cv.z;
      float v3 = cv.w > 0.f ? cv.w : ALPHA * cv.w;
      l[4*q] = v0; l[4*q+1] = v1; l[4*q+2] = v2; l[4*q+3] = v3;
      me = fmaxf(me, fmaxf(v0, v2));
      mo = fmaxf(mo, fmaxf(v1, v3));
    }
    #pragma unroll
    for (int s = 32; s >= 1; s >>= 1) {
      me = fmaxf(me, __shfl_xor(me, s, 64));
      mo = fmaxf(mo, __shfl_xor(mo, s, 64));
    }
    if (lane == 0) { redm[wv][0] = me; redm[wv][1] = mo; }
    __syncthreads();
    M0 = fmaxf(fmaxf(redm[0][0], redm[1][0]), fmaxf(redm[2][0], redm[3][0]));
    M1 = fmaxf(fmaxf(redm[0][1], redm[1][1]), fmaxf(redm[2][1], redm[3][1]));
    __syncthreads();
    float se = 0.f, so = 0.f;
    #pragma unroll
    for (int q = 0; q < 8; ++q) {
      se += __expf(l[2*q]     - M0);
      so += __expf(l[2*q + 1] - M1);
    }
    #pragma unroll
    for (int s = 32; s >= 1; s >>= 1) {
      se += __shfl_xor(se, s, 64);
      so += __shfl_xor(so, s, 64);
    }
    if (lane == 0) { redm[wv][0] = se; redm[wv][1] = so; }
    __syncthreads();
    const float P0 = redm[0][0] + redm[1][0] + redm[2][0] + redm[3][0];
    const float P1 = redm[0][1] + redm[1][1] + redm[2][1] + redm[3][1];

    // ---- weights + colsum over this block's 64 register-resident h rows ----
    const float Mt = firstHalf ? M0 : M1;
    const float Pt = firstHalf ? P0 : P1;
    float accA = 0.f, accU = 0.f;
    #pragma unroll
    for (int rr = 0; rr < 16; ++rr) {
      const int li = wv * 16 + rr;                 // e_s-local column index
      const float d = e_s[2 * li] + e_s[2 * li + 1];
      const float v = d > 0.f ? d : ALPHA * d;
      const float m  = fmaxf(Mt, v);
      const float eM = __expf(Mt - m);
      const float ev = __expf(v - m);
      const float Z  = eM * Pt + (float)HN * ev;
      accA = fmaf(eM / Z, hreg[rr], accA);
      accU = fmaf(ev / Z, hreg[rr], accU);
    }
    accbuf[wv][0][lane] = accA;
    accbuf[wv][1][lane] = accU;
    __syncthreads();
    if (tid < 64) {
      const float sA = accbuf[0][0][tid] + accbuf[1][0][tid] + accbuf[2][0][tid] + accbuf[3][0][tid];
      const float sU = accbuf[0][1][tid] + accbuf[1][1][tid] + accbuf[2][1][tid] + accbuf[3][1][tid];
      float* A = ws + (firstHalf ? WS_A0 : WS_A1) + (size_t)b * FF;
      atomicAdd(&A[tid], sA);                       // device-coherent RMWs
      atomicAdd(ws + WS_U + (size_t)b * FF + tid, sU);
    }
  }
  flag_bar(flags, slot, 2, tid, lane);   // A0/A1/u of this batch complete

  // ========== Phase D: each block writes its OWN 64 rows (per-batch data) ==========
  {
    float4* out4 = reinterpret_cast<float4*>(out);
    if (firstHalf) {
      const float* c = ws + WS_C + (size_t)b * NN_;
      const float4* A04 = reinterpret_cast<const float4*>(ws + WS_A0 + (size_t)b * FF);
      const float4* A14 = reinterpret_cast<const float4*>(ws + WS_A1 + (size_t)b * FF);
      #pragma unroll
      for (int it = 0; it < 4; ++it) {
        const int t    = it * NT + tid;          // 0..1023
        const int rloc = t >> 4;
        const int fg   = t & 15;
        const int i    = jb + rloc;              // row within batch (top half)
        float c0 = c[2 * i], c1 = c[2 * i + 1];
        c0 = c0 > 0.f ? c0 : ALPHA * c0;
        c1 = c1 > 0.f ? c1 : ALPHA * c1;
        const float al = __expf(c0 - M0);
        const float be = __expf(c1 - M1);
        const float4 A0v = A04[fg];
        const float4 A1v = A14[fg];
        float4 v;
        v.x = al * A0v.x + be * A1v.x;
        v.y = al * A0v.y + be * A1v.y;
        v.z = al * A0v.z + be * A1v.z;
        v.w = al * A0v.w + be * A1v.w;
        v.x = v.x > 0.f ? v.x : expm1f(v.x);
        v.y = v.y > 0.f ? v.y : expm1f(v.y);
        v.z = v.z > 0.f ? v.z : expm1f(v.z);
        v.w = v.w > 0.f ? v.w : expm1f(v.w);
        out4[((size_t)b * NN_ + i) * 16 + fg] = v;
      }
    } else {
      const float4* U4 = reinterpret_cast<const float4*>(ws + WS_U + (size_t)b * FF);
      #pragma unroll
      for (int it = 0; it < 4; ++it) {
        const int t    = it * NT + tid;
        const int rloc = t >> 4;
        const int fg   = t & 15;
        const int i    = jb + rloc;
        float4 v = U4[fg];
        v.x = v.x > 0.f ? v.x : expm1f(v.x);
        v.y = v.y > 0.f ? v.y : expm1f(v.y);
        v.z = v.z > 0.f ? v.z : expm1f(v.z);
        v.w = v.w > 0.f ? v.w : expm1f(v.w);
        out4[((size_t)b * NN_ + i) * 16 + fg] = v;
      }
    }
  }
}

extern "C" void kernel_launch(void* const* d_in, const int* in_sizes, int n_in,
                              void* d_out, int out_size, void* d_ws, size_t ws_size,
                              hipStream_t stream) {
  (void)in_sizes; (void)n_in; (void)out_size; (void)ws_size;
  const float* inp = (const float*)d_in[0];
  const float* W   = (const float*)d_in[1];
  const float* a   = (const float*)d_in[2];
  float* out = (float*)d_out;
  float* ws  = (float*)d_ws;

  // zero A0/A1/U accumulators + flag slots (replay-safe, stream-ordered)
  hipMemsetAsync((char*)d_ws + WS_A0 * sizeof(float), 0, 4096, stream);
  hipLaunchKernelGGL(fused, dim3(NBLK), dim3(NT), 0, stream, inp, W, a, ws, out);
}